// Round 17
// baseline (192.768 us; speedup 1.0000x reference)
//
#include <hip/hip_runtime.h>

// Problem constants
#define BATCH 16
#define NROW  10647
#define ROWF  85          // 4 box + 1 obj + 80 cls
#define NCLS  80
#define KTOP  2048
#define MPAD  16384       // next pow2 >= NROW
#define SCORE_THR 0.5f
#define IOU_THR   0.5f

typedef unsigned long long u64;
typedef unsigned int u32;

__device__ __forceinline__ u32 enc_f32(float f) {
    u32 u = __float_as_uint(f);
    return (u & 0x80000000u) ? ~u : (u | 0x80000000u);
}
__device__ __forceinline__ float dec_f32(u32 e) {
    u32 u = (e & 0x80000000u) ? (e & 0x7FFFFFFFu) : ~e;
    return __uint_as_float(u);
}
__device__ __forceinline__ float bcast(float v, int ii) {
    return __uint_as_float(__builtin_amdgcn_readlane(__float_as_uint(v), ii));
}
__device__ __forceinline__ u64 rl64(u64 v, int l) {
    u32 lo = __builtin_amdgcn_readlane((u32)(v & 0xFFFFFFFFull), l);
    u32 hi = __builtin_amdgcn_readlane((u32)(v >> 32), l);
    return ((u64)hi << 32) | (u64)lo;
}
// async global->LDS, 16B per lane; lds dest = uniform base + lane*16
__device__ __forceinline__ void gload_lds16(const void* g, void* lds) {
    __builtin_amdgcn_global_load_lds(
        (const __attribute__((address_space(1))) void*)g,
        (__attribute__((address_space(3))) void*)lds, 16, 0, 0);
}
// LDS-ordered barrier WITHOUT vmcnt drain (keeps global loads in flight)
__device__ __forceinline__ void bar_lds() {
    asm volatile("s_waitcnt lgkmcnt(0)" ::: "memory");
    __builtin_amdgcn_s_barrier();
    __builtin_amdgcn_sched_barrier(0);
}

// ===========================================================================
// Register-resident bitonic sort: 256 threads x 8 elements, e = tid*8 + r.
// ===========================================================================
template<int J>
__device__ __forceinline__ void reg_pass(u64 v[8], int tid, int k) {
    #pragma unroll
    for (int r = 0; r < 8; ++r) {
        if (!(r & J)) {
            bool desc = (((tid * 8 + r) & k) == 0);
            u64 a = v[r], b = v[r | J];
            u64 mx = a > b ? a : b, mn = a > b ? b : a;
            v[r]     = desc ? mx : mn;
            v[r | J] = desc ? mn : mx;
        }
    }
}

__device__ __forceinline__ void shfl_pass(u64 v[8], int tid, int k, int d) {
    const bool upper = (tid & d) == 0;
    const bool desc = (((tid * 8) & k) == 0);
    const bool keepmax = (desc == upper);
    #pragma unroll
    for (int r = 0; r < 8; ++r) {
        u64 pv = __shfl_xor(v[r], d);
        u64 mx = v[r] > pv ? v[r] : pv, mn = v[r] > pv ? pv : v[r];
        v[r] = keepmax ? mx : mn;
    }
}

__device__ __forceinline__ void lds_pass(u64 v[8], int tid, u64* sm, int k, int d) {
    __syncthreads();
    #pragma unroll
    for (int r = 0; r < 8; ++r) sm[r * 256 + tid] = v[r];
    __syncthreads();
    const bool upper = (tid & d) == 0;
    const bool desc = (((tid * 8) & k) == 0);
    const bool keepmax = (desc == upper);
    const int pt = tid ^ d;
    #pragma unroll
    for (int r = 0; r < 8; ++r) {
        u64 pv = sm[r * 256 + pt];
        u64 mx = v[r] > pv ? v[r] : pv, mn = v[r] > pv ? pv : v[r];
        v[r] = keepmax ? mx : mn;
    }
}

__device__ __forceinline__ void sort2048_desc(u64 v[8], int tid, u64* sm) {
    reg_pass<1>(v, tid, 2);
    reg_pass<2>(v, tid, 4); reg_pass<1>(v, tid, 4);
    for (int k = 8; k <= 2048; k <<= 1) {
        for (int j = k >> 1; j >= 8; j >>= 1) {
            int d = j >> 3;
            if (d <= 32) shfl_pass(v, tid, k, d);
            else         lds_pass(v, tid, sm, k, d);
        }
        reg_pass<4>(v, tid, k); reg_pass<2>(v, tid, k); reg_pass<1>(v, tid, k);
    }
}

// Bitonic cleanup (all-descending), j = 1024..1 — for the top-2048 merge.
__device__ __forceinline__ void cleanup2048_desc(u64 v[8], int tid, u64* sm) {
    lds_pass(v, tid, sm, 4096, 128);   // j = 1024
    lds_pass(v, tid, sm, 4096, 64);    // j = 512
    for (int d = 32; d >= 1; d >>= 1) shfl_pass(v, tid, 4096, d);
    reg_pass<4>(v, tid, 4096); reg_pass<2>(v, tid, 4096); reg_pass<1>(v, tid, 4096);
}

// ---------------------------------------------------------------------------
// Kernel 1: scores -> sortable u64 keys.  grid (96, BATCH), block 256.
// ---------------------------------------------------------------------------
__global__ void score_kernel(const float* __restrict__ yp, u64* __restrict__ keys) {
    __shared__ float tile[128 * ROWF];   // 43520 B
    const int tileIdx = blockIdx.x;
    const int b = blockIdx.y;
    const int tid = threadIdx.x;
    const int batch_lim = NROW * ROWF;       // 904995
    const int tile_base = tileIdx * 128 * ROWF;

    if (tile_base < batch_lim) {
        const float* src = yp + (long long)b * batch_lim + tile_base;
        int lim_e = batch_lim - tile_base;
        if (lim_e > 128 * ROWF) lim_e = 128 * ROWF;
        const int head = (4 - ((3 * b) & 3)) & 3;
        if (lim_e >= 8) {
            const int nv = (lim_e - head) >> 2;
            for (int e = tid; e < head; e += 256) tile[e] = src[e];
            const float4* s4 = (const float4*)(src + head);
            for (int q = tid; q < nv; q += 256) {
                float4 v = s4[q];
                int o = head + q * 4;
                tile[o] = v.x; tile[o + 1] = v.y; tile[o + 2] = v.z; tile[o + 3] = v.w;
            }
            for (int e = head + nv * 4 + tid; e < lim_e; e += 256) tile[e] = src[e];
        } else {
            for (int e = tid; e < lim_e; e += 256) tile[e] = src[e];
        }
    }
    __syncthreads();

    {
        const int row = tid >> 1;                // 0..127
        const int half = tid & 1;                // 0: cls 0..39, 1: cls 40..79
        int gr = tileIdx * 128 + row;
        const float* r = &tile[row * ROWF];
        float m = r[5 + half * 40];
        #pragma unroll
        for (int c = 1; c < 40; ++c) m = fmaxf(m, r[5 + half * 40 + c]);
        float mo = __uint_as_float(__shfl_xor(__float_as_uint(m), 1));
        if (half == 0 && gr < NROW) {
            float s = r[4] * fmaxf(m, mo);
            keys[(long long)b * MPAD + gr] =
                ((u64)enc_f32(s) << 32) | (u64)(0xFFFFFFFFu - (u32)gr);
        } else if (half == 0) {
            keys[(long long)b * MPAD + gr] = 0ULL;   // gr in [NROW, 12288)
        }
    }
}

// ---------------------------------------------------------------------------
// Kernel 2a: sort each 2048-chunk descending.  grid (6, BATCH), block 256.
// ---------------------------------------------------------------------------
__global__ void chunk_sort_kernel(u64* __restrict__ keys) {
    __shared__ u64 sm[2048];
    const int b = blockIdx.y, c = blockIdx.x, tid = threadIdx.x;
    u64* base = keys + (long long)b * MPAD + c * 2048;
    u64 v[8];
    #pragma unroll
    for (int r = 0; r < 8; ++r) v[r] = base[tid * 8 + r];
    sort2048_desc(v, tid, sm);
    #pragma unroll
    for (int r = 0; r < 8; ++r) base[tid * 8 + r] = v[r];
}

// ---------------------------------------------------------------------------
// Kernel 2b: round 1 — (0,1)->B0, (2,3)->B1, (4,5)->B2.  grid (3, BATCH).
// ---------------------------------------------------------------------------
__global__ void merge_r1_kernel(const u64* __restrict__ keysA, u64* __restrict__ keysB) {
    __shared__ u64 sm[2048];
    const int b = blockIdx.y, c = blockIdx.x, tid = threadIdx.x;
    const u64* a = keysA + (long long)b * MPAD + c * 4096;
    u64 v[8];
    #pragma unroll
    for (int r = 0; r < 8; ++r) {
        int e = tid * 8 + r;
        u64 va = a[e], vb = a[4095 - e];
        v[r] = va > vb ? va : vb;
    }
    cleanup2048_desc(v, tid, sm);
    u64* d = keysB + (long long)b * MPAD + c * 2048;
    #pragma unroll
    for (int r = 0; r < 8; ++r) d[tid * 8 + r] = v[r];
}

// ---------------------------------------------------------------------------
// Kernel 2c (fused r2+r3): (B0,B1)->X, (X,B2)->final top-2048 + gather.
// grid: BATCH, block 256.  Bit-identical tree to the 3-kernel chain.
// ---------------------------------------------------------------------------
__global__ void merge_r23_gather_kernel(const u64* __restrict__ keysB,
                                        const float* __restrict__ yp,
                                        float* __restrict__ sx1, float* __restrict__ sy1,
                                        float* __restrict__ sx2, float* __restrict__ sy2,
                                        float* __restrict__ sar, float* __restrict__ ssc) {
    __shared__ u64 sm[2048];
    const int b = blockIdx.x, tid = threadIdx.x;
    const u64* a = keysB + (long long)b * MPAD;
    u64 v[8];
    #pragma unroll
    for (int r = 0; r < 8; ++r) {
        int e = tid * 8 + r;
        u64 va = a[e], vb = a[2048 + 2047 - e];
        v[r] = va > vb ? va : vb;
    }
    cleanup2048_desc(v, tid, sm);
    #pragma unroll
    for (int r = 0; r < 8; ++r) {
        int e = tid * 8 + r;
        u64 vb = a[4096 + 2047 - e];
        v[r] = v[r] > vb ? v[r] : vb;
    }
    cleanup2048_desc(v, tid, sm);

    #pragma unroll
    for (int r = 0; r < 8; ++r) {
        u64 key = v[r];
        float s = dec_f32((u32)(key >> 32));
        u32 idx = 0xFFFFFFFFu - (u32)(key & 0xFFFFFFFFu);
        const float* rp = yp + (long long)b * NROW * ROWF + (long long)idx * ROWF;
        float x = rp[0], y = rp[1], w = rp[2], h = rp[3];
        float hx = w * 0.5f, hy = h * 0.5f;
        float a1 = x - hx, b1 = y - hy, a2 = x + hx, b2 = y + hy;
        int o = b * KTOP + tid * 8 + r;
        sx1[o] = a1; sy1[o] = b1; sx2[o] = a2; sy2[o] = b2;
        sar[o] = fmaxf(a2 - a1, 0.f) * fmaxf(b2 - b1, 0.f);
        ssc[o] = s;
    }
}

// ---------------------------------------------------------------------------
// Kernel 3: pairwise suppression bitmask + dense diagonal side-array.
// grid (132, BATCH), block 256.
// ---------------------------------------------------------------------------
__global__ void mask_kernel(const float* __restrict__ sx1, const float* __restrict__ sy1,
                            const float* __restrict__ sx2, const float* __restrict__ sy2,
                            const float* __restrict__ sar, u64* __restrict__ mask,
                            u64* __restrict__ diag) {
    const int b = blockIdx.y;
    const int t = blockIdx.x * 4 + (threadIdx.x >> 6);   // 0..527
    const int lane = threadIdx.x & 63;

    int rb = (int)((65.0f - sqrtf(4225.0f - 8.0f * (float)t)) * 0.5f);
    while (rb * (65 - rb) / 2 > t) --rb;
    while ((rb + 1) * (64 - rb) / 2 <= t) ++rb;
    const int cb = rb + t - rb * (65 - rb) / 2;

    const int oi = b * KTOP + rb * 64 + lane;
    const int oj = b * KTOP + cb * 64 + lane;
    const float rx1 = sx1[oi], ry1 = sy1[oi], rx2 = sx2[oi], ry2 = sy2[oi], ra = sar[oi];
    const float cx1 = sx1[oj], cy1 = sy1[oj], cx2 = sx2[oj], cy2 = sy2[oj], ca = sar[oj];
    const bool dg = (rb == cb);

    u64 myword = 0ULL;
    for (int ii = 0; ii < 64; ++ii) {
        float ax1 = bcast(rx1, ii), ay1 = bcast(ry1, ii);
        float ax2 = bcast(rx2, ii), ay2 = bcast(ry2, ii);
        float aa  = bcast(ra,  ii);
        float ix1 = fmaxf(ax1, cx1);
        float iy1 = fmaxf(ay1, cy1);
        float ix2 = fminf(ax2, cx2);
        float iy2 = fminf(ay2, cy2);
        float inter = fmaxf(ix2 - ix1, 0.f) * fmaxf(iy2 - iy1, 0.f);
        float uni = aa + ca - inter;
        float iou = inter / fmaxf(uni, 1e-9f);
        bool cond = (iou > IOU_THR) && (!dg || (lane > ii));
        u64 bal = __ballot(cond);
        if (lane == ii) myword = bal;
    }
    mask[(long long)(b * KTOP + rb * 64 + lane) * 32 + cb] = myword;
    if (dg) diag[(long long)b * 2048 + rb * 64 + lane] = myword;
}

// ---------------------------------------------------------------------------
// Kernel 4: greedy reduce, cooperative split.  CHANGE vs r16: wave0's chain
// reads dia words via SCALAR loads (s_load) at wave-uniform addresses from
// the dense diag array — no v_readlane broadcasts, no VALU->SALU hazards,
// no per-lane dia prefetch.  Everything else identical.
// grid: BATCH, block: 256.
// ---------------------------------------------------------------------------
__global__ void nms_out_kernel(const float* __restrict__ sx1, const float* __restrict__ sy1,
                               const float* __restrict__ sx2, const float* __restrict__ sy2,
                               const float* __restrict__ ssc,
                               const u64* __restrict__ mask,
                               const u64* __restrict__ diag, float* __restrict__ out) {
    __shared__ u64 slots[4][2048];  // 64 KiB ring, linear [row][col] per block
    __shared__ u64 pend[8][32];     // supp partials
    __shared__ u64 curs;            // published cur of current block
    __shared__ u64 sbits64[32];     // score-valid bits
    __shared__ u64 keepw[32];
    const int b = blockIdx.x;
    const int tid = threadIdx.x;
    const int lane = tid & 63;
    const int wave = tid >> 6;
    const u64* mb = mask + (long long)(b * KTOP) * 32;
    const char* mbc = (const char*)mb;
    const u64* dg = diag + (long long)b * 2048;

    auto issue_block = [&](int B) {
        const char* src = mbc + (size_t)B * 16384;
        char* dst = (char*)&slots[B & 3][0];
        #pragma unroll
        for (int i = 0; i < 16; ++i)
            gload_lds16(src + i * 1024 + lane * 16, dst + i * 1024);
    };

    // ---- prologue ----
    {
        const float* sp = ssc + b * KTOP + tid * 8;
        float4 sa = *(const float4*)(sp);
        float4 sb = *(const float4*)(sp + 4);
        unsigned bits =
            (unsigned)(sa.x > SCORE_THR)       | ((unsigned)(sa.y > SCORE_THR) << 1) |
            ((unsigned)(sa.z > SCORE_THR) << 2) | ((unsigned)(sa.w > SCORE_THR) << 3) |
            ((unsigned)(sb.x > SCORE_THR) << 4) | ((unsigned)(sb.y > SCORE_THR) << 5) |
            ((unsigned)(sb.z > SCORE_THR) << 6) | ((unsigned)(sb.w > SCORE_THR) << 7);
        ((unsigned char*)sbits64)[tid] = (unsigned char)bits;
    }
    if (wave >= 1) issue_block(wave - 1);   // blocks 0,1,2
    __syncthreads();   // full drain: blocks 0-2 resident, sbits ready

    u64 myw = 0ULL;
    if (wave == 0 && lane < 32) myw = sbits64[lane];

    // ---- main loop ----
    #pragma unroll 1
    for (int w = 0; w < 32; ++w) {
        const u64* blk = &slots[w & 3][0];

        if (wave == 0) {
            // current keep word -> uniform via dynamic-index readlane
            u64 cur = rl64(myw, w);
            // serial chain: 4 batches of (16 scalar dia loads + 16 SALU steps).
            // dgw is wave-uniform -> compiler emits s_load into SGPRs.
            const u64* dgw = dg + w * 64;
            #pragma unroll
            for (int p = 0; p < 4; ++p) {
                u64 dd[16];
                #pragma unroll
                for (int i = 0; i < 16; ++i) dd[i] = dgw[p * 16 + i];
                #pragma unroll
                for (int i = 0; i < 16; ++i) {
                    u64 m = ((cur >> (p * 16 + i)) & 1ULL) ? dd[i] : 0ULL;
                    cur &= ~m;
                }
            }
            if (lane == 0) curs = cur;
        } else {
            const int rr = wave - 1;
            if ((w % 3) == rr && w + 3 < 32) issue_block(w + 3);
            if (((w + 1) % 3) == rr)
                asm volatile("s_waitcnt vmcnt(0)" ::: "memory");  // my block w+1 landed
        }
        bar_lds();   // barrier 1: cur visible; block w resident for everyone

        // phase 2: cooperative supp partials (2048 words / 256 threads)
        {
            u64 curv = curs;                     // LDS broadcast
            const int col = tid & 31;
            const int rg  = tid >> 5;            // row group 0..7 (rows rg*8..+8)
            const u64* rp = blk + (size_t)rg * 256 + col;
            u32 bits8 = (u32)(curv >> (rg * 8)) & 0xFFu;
            u64 acc = 0ULL;
            #pragma unroll
            for (int i = 0; i < 8; ++i) {
                u64 t = rp[(size_t)i * 32];
                acc |= ((bits8 >> i) & 1u) ? t : 0ULL;
            }
            pend[rg][col] = acc;
        }
        bar_lds();   // barrier 2: pend complete

        if (wave == 0 && lane < 32) {
            u64 cur = curs;
            u64 s = ((pend[0][lane] | pend[1][lane]) | (pend[2][lane] | pend[3][lane]))
                  | ((pend[4][lane] | pend[5][lane]) | (pend[6][lane] | pend[7][lane]));
            if (lane == w) myw = cur;
            else if (lane > w) myw &= ~s;
        }
        // wave0's pend reads complete before it reaches barrier1 of iter w+1,
        // which is when pend can next be overwritten -> no extra barrier.
    }

    if (wave == 0 && lane < 32) keepw[lane] = myw;
    __syncthreads();

    for (int t = tid; t < KTOP; t += 256) {
        int o = b * KTOP + t;
        float f = ((keepw[t >> 6] >> (t & 63)) & 1ULL) ? 1.0f : 0.0f;
        float* op = out + (long long)o * 5;
        op[0] = sx1[o] * f;
        op[1] = sy1[o] * f;
        op[2] = sx2[o] * f;
        op[3] = sy2[o] * f;
        op[4] = ssc[o] * f;
    }
}

// ---------------------------------------------------------------------------
extern "C" void kernel_launch(void* const* d_in, const int* in_sizes, int n_in,
                              void* d_out, int out_size, void* d_ws, size_t ws_size,
                              hipStream_t stream) {
    const float* yp = (const float*)d_in[0];
    float* out = (float*)d_out;
    char* ws = (char*)d_ws;

    // Workspace layout (aliasing safe by kernel ordering):
    //   [0, 2MiB)   keysA   (dead after merge_r1)
    //   [2, 4MiB)   keysB   (dead after merge_r23)
    //   [0, 8MiB)   mask    (written by mask_kernel, after keys die)
    //   [8MiB, +768KiB)  SoA arrays
    //   [+256KiB)   diag array
    const size_t KEYS_BYTES = (size_t)BATCH * MPAD * sizeof(u64);        // 2 MiB
    const size_t MASK_BYTES = (size_t)BATCH * KTOP * 32 * sizeof(u64);   // 8 MiB
    const size_t SOA_BYTES  = (size_t)6 * BATCH * KTOP * sizeof(float);  // 768 KiB
    u64* keysA = (u64*)ws;
    u64* keysB = (u64*)(ws + KEYS_BYTES);
    u64* mask  = (u64*)ws;
    float* soa = (float*)(ws + MASK_BYTES);
    u64* diag  = (u64*)(ws + MASK_BYTES + SOA_BYTES);
    const int SA = BATCH * KTOP;
    float* sx1 = soa + 0 * SA;
    float* sy1 = soa + 1 * SA;
    float* sx2 = soa + 2 * SA;
    float* sy2 = soa + 3 * SA;
    float* sar = soa + 4 * SA;
    float* ssc = soa + 5 * SA;

    score_kernel<<<dim3(96, BATCH), 256, 0, stream>>>(yp, keysA);
    chunk_sort_kernel<<<dim3(6, BATCH), 256, 0, stream>>>(keysA);
    merge_r1_kernel<<<dim3(3, BATCH), 256, 0, stream>>>(keysA, keysB);
    merge_r23_gather_kernel<<<BATCH, 256, 0, stream>>>(keysB, yp,
                                                       sx1, sy1, sx2, sy2, sar, ssc);
    mask_kernel<<<dim3(132, BATCH), 256, 0, stream>>>(sx1, sy1, sx2, sy2, sar,
                                                      mask, diag);
    nms_out_kernel<<<BATCH, 256, 0, stream>>>(sx1, sy1, sx2, sy2, ssc,
                                              mask, diag, out);
}

// Round 18
// 161.618 us; speedup vs baseline: 1.1927x; 1.1927x over previous
//
#include <hip/hip_runtime.h>

// Problem constants
#define BATCH 16
#define NROW  10647
#define ROWF  85          // 4 box + 1 obj + 80 cls
#define NCLS  80
#define KTOP  2048
#define MPAD  16384       // next pow2 >= NROW
#define SCORE_THR 0.5f
#define IOU_THR   0.5f

typedef unsigned long long u64;
typedef unsigned int u32;

__device__ __forceinline__ u32 enc_f32(float f) {
    u32 u = __float_as_uint(f);
    return (u & 0x80000000u) ? ~u : (u | 0x80000000u);
}
__device__ __forceinline__ float dec_f32(u32 e) {
    u32 u = (e & 0x80000000u) ? (e & 0x7FFFFFFFu) : ~e;
    return __uint_as_float(u);
}
__device__ __forceinline__ float bcast(float v, int ii) {
    return __uint_as_float(__builtin_amdgcn_readlane(__float_as_uint(v), ii));
}
__device__ __forceinline__ u64 rl64(u64 v, int l) {
    u32 lo = __builtin_amdgcn_readlane((u32)(v & 0xFFFFFFFFull), l);
    u32 hi = __builtin_amdgcn_readlane((u32)(v >> 32), l);
    return ((u64)hi << 32) | (u64)lo;
}
// async global->LDS, 16B per lane; lds dest = uniform base + lane*16
__device__ __forceinline__ void gload_lds16(const void* g, void* lds) {
    __builtin_amdgcn_global_load_lds(
        (const __attribute__((address_space(1))) void*)g,
        (__attribute__((address_space(3))) void*)lds, 16, 0, 0);
}
// LDS-ordered barrier WITHOUT vmcnt drain (keeps global loads in flight)
__device__ __forceinline__ void bar_lds() {
    asm volatile("s_waitcnt lgkmcnt(0)" ::: "memory");
    __builtin_amdgcn_s_barrier();
    __builtin_amdgcn_sched_barrier(0);
}

// ===========================================================================
// Register-resident bitonic sort: 256 threads x 8 elements, e = tid*8 + r.
// ===========================================================================
template<int J>
__device__ __forceinline__ void reg_pass(u64 v[8], int tid, int k) {
    #pragma unroll
    for (int r = 0; r < 8; ++r) {
        if (!(r & J)) {
            bool desc = (((tid * 8 + r) & k) == 0);
            u64 a = v[r], b = v[r | J];
            u64 mx = a > b ? a : b, mn = a > b ? b : a;
            v[r]     = desc ? mx : mn;
            v[r | J] = desc ? mn : mx;
        }
    }
}

__device__ __forceinline__ void shfl_pass(u64 v[8], int tid, int k, int d) {
    const bool upper = (tid & d) == 0;
    const bool desc = (((tid * 8) & k) == 0);
    const bool keepmax = (desc == upper);
    #pragma unroll
    for (int r = 0; r < 8; ++r) {
        u64 pv = __shfl_xor(v[r], d);
        u64 mx = v[r] > pv ? v[r] : pv, mn = v[r] > pv ? pv : v[r];
        v[r] = keepmax ? mx : mn;
    }
}

__device__ __forceinline__ void lds_pass(u64 v[8], int tid, u64* sm, int k, int d) {
    __syncthreads();
    #pragma unroll
    for (int r = 0; r < 8; ++r) sm[r * 256 + tid] = v[r];
    __syncthreads();
    const bool upper = (tid & d) == 0;
    const bool desc = (((tid * 8) & k) == 0);
    const bool keepmax = (desc == upper);
    const int pt = tid ^ d;
    #pragma unroll
    for (int r = 0; r < 8; ++r) {
        u64 pv = sm[r * 256 + pt];
        u64 mx = v[r] > pv ? v[r] : pv, mn = v[r] > pv ? pv : v[r];
        v[r] = keepmax ? mx : mn;
    }
}

__device__ __forceinline__ void sort2048_desc(u64 v[8], int tid, u64* sm) {
    reg_pass<1>(v, tid, 2);
    reg_pass<2>(v, tid, 4); reg_pass<1>(v, tid, 4);
    for (int k = 8; k <= 2048; k <<= 1) {
        for (int j = k >> 1; j >= 8; j >>= 1) {
            int d = j >> 3;
            if (d <= 32) shfl_pass(v, tid, k, d);
            else         lds_pass(v, tid, sm, k, d);
        }
        reg_pass<4>(v, tid, k); reg_pass<2>(v, tid, k); reg_pass<1>(v, tid, k);
    }
}

// Bitonic cleanup (all-descending), j = 1024..1 — for the top-2048 merge.
__device__ __forceinline__ void cleanup2048_desc(u64 v[8], int tid, u64* sm) {
    lds_pass(v, tid, sm, 4096, 128);   // j = 1024
    lds_pass(v, tid, sm, 4096, 64);    // j = 512
    for (int d = 32; d >= 1; d >>= 1) shfl_pass(v, tid, 4096, d);
    reg_pass<4>(v, tid, 4096); reg_pass<2>(v, tid, 4096); reg_pass<1>(v, tid, 4096);
}

// ---------------------------------------------------------------------------
// Kernel 1: scores -> sortable u64 keys.  grid (96, BATCH), block 256.
// ---------------------------------------------------------------------------
__global__ void score_kernel(const float* __restrict__ yp, u64* __restrict__ keys) {
    __shared__ float tile[128 * ROWF];   // 43520 B
    const int tileIdx = blockIdx.x;
    const int b = blockIdx.y;
    const int tid = threadIdx.x;
    const int batch_lim = NROW * ROWF;       // 904995
    const int tile_base = tileIdx * 128 * ROWF;

    if (tile_base < batch_lim) {
        const float* src = yp + (long long)b * batch_lim + tile_base;
        int lim_e = batch_lim - tile_base;
        if (lim_e > 128 * ROWF) lim_e = 128 * ROWF;
        const int head = (4 - ((3 * b) & 3)) & 3;
        if (lim_e >= 8) {
            const int nv = (lim_e - head) >> 2;
            for (int e = tid; e < head; e += 256) tile[e] = src[e];
            const float4* s4 = (const float4*)(src + head);
            for (int q = tid; q < nv; q += 256) {
                float4 v = s4[q];
                int o = head + q * 4;
                tile[o] = v.x; tile[o + 1] = v.y; tile[o + 2] = v.z; tile[o + 3] = v.w;
            }
            for (int e = head + nv * 4 + tid; e < lim_e; e += 256) tile[e] = src[e];
        } else {
            for (int e = tid; e < lim_e; e += 256) tile[e] = src[e];
        }
    }
    __syncthreads();

    {
        const int row = tid >> 1;                // 0..127
        const int half = tid & 1;                // 0: cls 0..39, 1: cls 40..79
        int gr = tileIdx * 128 + row;
        const float* r = &tile[row * ROWF];
        float m = r[5 + half * 40];
        #pragma unroll
        for (int c = 1; c < 40; ++c) m = fmaxf(m, r[5 + half * 40 + c]);
        float mo = __uint_as_float(__shfl_xor(__float_as_uint(m), 1));
        if (half == 0 && gr < NROW) {
            float s = r[4] * fmaxf(m, mo);
            keys[(long long)b * MPAD + gr] =
                ((u64)enc_f32(s) << 32) | (u64)(0xFFFFFFFFu - (u32)gr);
        } else if (half == 0) {
            keys[(long long)b * MPAD + gr] = 0ULL;   // gr in [NROW, 12288)
        }
    }
}

// ---------------------------------------------------------------------------
// Kernel 2a: sort each 2048-chunk descending.  grid (6, BATCH), block 256.
// ---------------------------------------------------------------------------
__global__ void chunk_sort_kernel(u64* __restrict__ keys) {
    __shared__ u64 sm[2048];
    const int b = blockIdx.y, c = blockIdx.x, tid = threadIdx.x;
    u64* base = keys + (long long)b * MPAD + c * 2048;
    u64 v[8];
    #pragma unroll
    for (int r = 0; r < 8; ++r) v[r] = base[tid * 8 + r];
    sort2048_desc(v, tid, sm);
    #pragma unroll
    for (int r = 0; r < 8; ++r) base[tid * 8 + r] = v[r];
}

// ---------------------------------------------------------------------------
// Kernel 2b: round 1 — (0,1)->B0, (2,3)->B1, (4,5)->B2.  grid (3, BATCH).
// ---------------------------------------------------------------------------
__global__ void merge_r1_kernel(const u64* __restrict__ keysA, u64* __restrict__ keysB) {
    __shared__ u64 sm[2048];
    const int b = blockIdx.y, c = blockIdx.x, tid = threadIdx.x;
    const u64* a = keysA + (long long)b * MPAD + c * 4096;
    u64 v[8];
    #pragma unroll
    for (int r = 0; r < 8; ++r) {
        int e = tid * 8 + r;
        u64 va = a[e], vb = a[4095 - e];
        v[r] = va > vb ? va : vb;
    }
    cleanup2048_desc(v, tid, sm);
    u64* d = keysB + (long long)b * MPAD + c * 2048;
    #pragma unroll
    for (int r = 0; r < 8; ++r) d[tid * 8 + r] = v[r];
}

// ---------------------------------------------------------------------------
// Kernel 2c (fused r2+r3): (B0,B1)->X, (X,B2)->final top-2048 + gather.
// grid: BATCH, block 256.  Bit-identical tree to the 3-kernel chain.
// ---------------------------------------------------------------------------
__global__ void merge_r23_gather_kernel(const u64* __restrict__ keysB,
                                        const float* __restrict__ yp,
                                        float* __restrict__ sx1, float* __restrict__ sy1,
                                        float* __restrict__ sx2, float* __restrict__ sy2,
                                        float* __restrict__ sar, float* __restrict__ ssc) {
    __shared__ u64 sm[2048];
    const int b = blockIdx.x, tid = threadIdx.x;
    const u64* a = keysB + (long long)b * MPAD;
    u64 v[8];
    #pragma unroll
    for (int r = 0; r < 8; ++r) {
        int e = tid * 8 + r;
        u64 va = a[e], vb = a[2048 + 2047 - e];
        v[r] = va > vb ? va : vb;
    }
    cleanup2048_desc(v, tid, sm);
    #pragma unroll
    for (int r = 0; r < 8; ++r) {
        int e = tid * 8 + r;
        u64 vb = a[4096 + 2047 - e];
        v[r] = v[r] > vb ? v[r] : vb;
    }
    cleanup2048_desc(v, tid, sm);

    #pragma unroll
    for (int r = 0; r < 8; ++r) {
        u64 key = v[r];
        float s = dec_f32((u32)(key >> 32));
        u32 idx = 0xFFFFFFFFu - (u32)(key & 0xFFFFFFFFu);
        const float* rp = yp + (long long)b * NROW * ROWF + (long long)idx * ROWF;
        float x = rp[0], y = rp[1], w = rp[2], h = rp[3];
        float hx = w * 0.5f, hy = h * 0.5f;
        float a1 = x - hx, b1 = y - hy, a2 = x + hx, b2 = y + hy;
        int o = b * KTOP + tid * 8 + r;
        sx1[o] = a1; sy1[o] = b1; sx2[o] = a2; sy2[o] = b2;
        sar[o] = fmaxf(a2 - a1, 0.f) * fmaxf(b2 - b1, 0.f);
        ssc[o] = s;
    }
}

// ---------------------------------------------------------------------------
// Kernel 3: pairwise suppression bitmask + dense diagonal side-array.
// grid (132, BATCH), block 256.
// ---------------------------------------------------------------------------
__global__ void mask_kernel(const float* __restrict__ sx1, const float* __restrict__ sy1,
                            const float* __restrict__ sx2, const float* __restrict__ sy2,
                            const float* __restrict__ sar, u64* __restrict__ mask,
                            u64* __restrict__ diag) {
    const int b = blockIdx.y;
    const int t = blockIdx.x * 4 + (threadIdx.x >> 6);   // 0..527
    const int lane = threadIdx.x & 63;

    int rb = (int)((65.0f - sqrtf(4225.0f - 8.0f * (float)t)) * 0.5f);
    while (rb * (65 - rb) / 2 > t) --rb;
    while ((rb + 1) * (64 - rb) / 2 <= t) ++rb;
    const int cb = rb + t - rb * (65 - rb) / 2;

    const int oi = b * KTOP + rb * 64 + lane;
    const int oj = b * KTOP + cb * 64 + lane;
    const float rx1 = sx1[oi], ry1 = sy1[oi], rx2 = sx2[oi], ry2 = sy2[oi], ra = sar[oi];
    const float cx1 = sx1[oj], cy1 = sy1[oj], cx2 = sx2[oj], cy2 = sy2[oj], ca = sar[oj];
    const bool dg = (rb == cb);

    u64 myword = 0ULL;
    for (int ii = 0; ii < 64; ++ii) {
        float ax1 = bcast(rx1, ii), ay1 = bcast(ry1, ii);
        float ax2 = bcast(rx2, ii), ay2 = bcast(ry2, ii);
        float aa  = bcast(ra,  ii);
        float ix1 = fmaxf(ax1, cx1);
        float iy1 = fmaxf(ay1, cy1);
        float ix2 = fminf(ax2, cx2);
        float iy2 = fminf(ay2, cy2);
        float inter = fmaxf(ix2 - ix1, 0.f) * fmaxf(iy2 - iy1, 0.f);
        float uni = aa + ca - inter;
        float iou = inter / fmaxf(uni, 1e-9f);
        bool cond = (iou > IOU_THR) && (!dg || (lane > ii));
        u64 bal = __ballot(cond);
        if (lane == ii) myword = bal;
    }
    mask[(long long)(b * KTOP + rb * 64 + lane) * 32 + cb] = myword;
    if (dg) diag[(long long)b * 2048 + rb * 64 + lane] = myword;
}

// ---------------------------------------------------------------------------
// Kernel 4 (proven r13/r16 variant): greedy reduce, cooperative split.
//   wave0: dia words in REGISTERS (vector-prefetched from dense diag array
//   one iter ahead — latency hidden under chain + barriers); cur via
//   dynamic-index readlane; serial chain in batched readlane + SALU.
//   waves1-3: 4-slot LDS prefetch ring (global_load_lds, counted vmcnt).
//   phase2: ALL 256 threads OR mask words into pend; wave0 folds+applies.
// grid: BATCH, block: 256.
// ---------------------------------------------------------------------------
__global__ void nms_out_kernel(const float* __restrict__ sx1, const float* __restrict__ sy1,
                               const float* __restrict__ sx2, const float* __restrict__ sy2,
                               const float* __restrict__ ssc,
                               const u64* __restrict__ mask,
                               const u64* __restrict__ diag, float* __restrict__ out) {
    __shared__ u64 slots[4][2048];  // 64 KiB ring, linear [row][col] per block
    __shared__ u64 pend[8][32];     // supp partials
    __shared__ u64 curs;            // published cur of current block
    __shared__ u64 sbits64[32];     // score-valid bits
    __shared__ u64 keepw[32];
    const int b = blockIdx.x;
    const int tid = threadIdx.x;
    const int lane = tid & 63;
    const int wave = tid >> 6;
    const u64* mb = mask + (long long)(b * KTOP) * 32;
    const char* mbc = (const char*)mb;
    const u64* dg = diag + (long long)b * 2048;

    auto issue_block = [&](int B) {
        const char* src = mbc + (size_t)B * 16384;
        char* dst = (char*)&slots[B & 3][0];
        #pragma unroll
        for (int i = 0; i < 16; ++i)
            gload_lds16(src + i * 1024 + lane * 16, dst + i * 1024);
    };

    // ---- prologue ----
    {
        const float* sp = ssc + b * KTOP + tid * 8;
        float4 sa = *(const float4*)(sp);
        float4 sb = *(const float4*)(sp + 4);
        unsigned bits =
            (unsigned)(sa.x > SCORE_THR)       | ((unsigned)(sa.y > SCORE_THR) << 1) |
            ((unsigned)(sa.z > SCORE_THR) << 2) | ((unsigned)(sa.w > SCORE_THR) << 3) |
            ((unsigned)(sb.x > SCORE_THR) << 4) | ((unsigned)(sb.y > SCORE_THR) << 5) |
            ((unsigned)(sb.z > SCORE_THR) << 6) | ((unsigned)(sb.w > SCORE_THR) << 7);
        ((unsigned char*)sbits64)[tid] = (unsigned char)bits;
    }
    u64 dia = 0ULL;
    if (wave == 0) dia = dg[lane];          // block 0 diagonal words
    if (wave >= 1) issue_block(wave - 1);   // blocks 0,1,2
    __syncthreads();   // full drain: blocks 0-2 resident, sbits + dia ready

    u64 myw = 0ULL;
    if (wave == 0 && lane < 32) myw = sbits64[lane];

    // ---- main loop ----
    #pragma unroll 1
    for (int w = 0; w < 32; ++w) {
        const u64* blk = &slots[w & 3][0];

        if (wave == 0) {
            // issue next block's dia load FIRST (latency hides under chain+barriers)
            u64 dia_next = 0ULL;
            if (w < 31) dia_next = dg[(w + 1) * 64 + lane];
            // current keep word -> uniform via dynamic-index readlane
            u64 cur = rl64(myw, w);
            // serial chain: 4 batches of (16 indep readlane-pairs + 16 SALU steps)
            #pragma unroll
            for (int p = 0; p < 4; ++p) {
                u64 dd[16];
                #pragma unroll
                for (int i = 0; i < 16; ++i) dd[i] = rl64(dia, p * 16 + i);
                #pragma unroll
                for (int i = 0; i < 16; ++i) {
                    u64 m = ((cur >> (p * 16 + i)) & 1ULL) ? dd[i] : 0ULL;
                    cur &= ~m;
                }
            }
            if (lane == 0) curs = cur;
            dia = dia_next;
        } else {
            const int rr = wave - 1;
            if ((w % 3) == rr && w + 3 < 32) issue_block(w + 3);
            if (((w + 1) % 3) == rr)
                asm volatile("s_waitcnt vmcnt(0)" ::: "memory");  // my block w+1 landed
        }
        bar_lds();   // barrier 1: cur visible; block w resident for everyone

        // phase 2: cooperative supp partials (2048 words / 256 threads)
        {
            u64 curv = curs;                     // LDS broadcast
            const int col = tid & 31;
            const int rg  = tid >> 5;            // row group 0..7 (rows rg*8..+8)
            const u64* rp = blk + (size_t)rg * 256 + col;
            u32 bits8 = (u32)(curv >> (rg * 8)) & 0xFFu;
            u64 acc = 0ULL;
            #pragma unroll
            for (int i = 0; i < 8; ++i) {
                u64 t = rp[(size_t)i * 32];
                acc |= ((bits8 >> i) & 1u) ? t : 0ULL;
            }
            pend[rg][col] = acc;
        }
        bar_lds();   // barrier 2: pend complete

        if (wave == 0 && lane < 32) {
            u64 cur = curs;
            u64 s = ((pend[0][lane] | pend[1][lane]) | (pend[2][lane] | pend[3][lane]))
                  | ((pend[4][lane] | pend[5][lane]) | (pend[6][lane] | pend[7][lane]));
            if (lane == w) myw = cur;
            else if (lane > w) myw &= ~s;
        }
        // wave0's pend reads complete before it reaches barrier1 of iter w+1,
        // which is when pend can next be overwritten -> no extra barrier.
    }

    if (wave == 0 && lane < 32) keepw[lane] = myw;
    __syncthreads();

    for (int t = tid; t < KTOP; t += 256) {
        int o = b * KTOP + t;
        float f = ((keepw[t >> 6] >> (t & 63)) & 1ULL) ? 1.0f : 0.0f;
        float* op = out + (long long)o * 5;
        op[0] = sx1[o] * f;
        op[1] = sy1[o] * f;
        op[2] = sx2[o] * f;
        op[3] = sy2[o] * f;
        op[4] = ssc[o] * f;
    }
}

// ---------------------------------------------------------------------------
extern "C" void kernel_launch(void* const* d_in, const int* in_sizes, int n_in,
                              void* d_out, int out_size, void* d_ws, size_t ws_size,
                              hipStream_t stream) {
    const float* yp = (const float*)d_in[0];
    float* out = (float*)d_out;
    char* ws = (char*)d_ws;

    // Workspace layout (aliasing safe by kernel ordering):
    //   [0, 2MiB)   keysA   (dead after merge_r1)
    //   [2, 4MiB)   keysB   (dead after merge_r23)
    //   [0, 8MiB)   mask    (written by mask_kernel, after keys die)
    //   [8MiB, +768KiB)  SoA arrays
    //   [+256KiB)   diag array
    const size_t KEYS_BYTES = (size_t)BATCH * MPAD * sizeof(u64);        // 2 MiB
    const size_t MASK_BYTES = (size_t)BATCH * KTOP * 32 * sizeof(u64);   // 8 MiB
    const size_t SOA_BYTES  = (size_t)6 * BATCH * KTOP * sizeof(float);  // 768 KiB
    u64* keysA = (u64*)ws;
    u64* keysB = (u64*)(ws + KEYS_BYTES);
    u64* mask  = (u64*)ws;
    float* soa = (float*)(ws + MASK_BYTES);
    u64* diag  = (u64*)(ws + MASK_BYTES + SOA_BYTES);
    const int SA = BATCH * KTOP;
    float* sx1 = soa + 0 * SA;
    float* sy1 = soa + 1 * SA;
    float* sx2 = soa + 2 * SA;
    float* sy2 = soa + 3 * SA;
    float* sar = soa + 4 * SA;
    float* ssc = soa + 5 * SA;

    score_kernel<<<dim3(96, BATCH), 256, 0, stream>>>(yp, keysA);
    chunk_sort_kernel<<<dim3(6, BATCH), 256, 0, stream>>>(keysA);
    merge_r1_kernel<<<dim3(3, BATCH), 256, 0, stream>>>(keysA, keysB);
    merge_r23_gather_kernel<<<BATCH, 256, 0, stream>>>(keysB, yp,
                                                       sx1, sy1, sx2, sy2, sar, ssc);
    mask_kernel<<<dim3(132, BATCH), 256, 0, stream>>>(sx1, sy1, sx2, sy2, sar,
                                                      mask, diag);
    nms_out_kernel<<<BATCH, 256, 0, stream>>>(sx1, sy1, sx2, sy2, ssc,
                                              mask, diag, out);
}

// Round 19
// 158.720 us; speedup vs baseline: 1.2145x; 1.0183x over previous
//
#include <hip/hip_runtime.h>

// Problem constants
#define BATCH 16
#define NROW  10647
#define ROWF  85          // 4 box + 1 obj + 80 cls
#define NCLS  80
#define KTOP  2048
#define MPAD  16384       // next pow2 >= NROW
#define SCORE_THR 0.5f
#define IOU_THR   0.5f
#define PKWORDS 34816     // 64 * S(32), packed mask words per batch

typedef unsigned long long u64;
typedef unsigned int u32;

__device__ __forceinline__ u32 enc_f32(float f) {
    u32 u = __float_as_uint(f);
    return (u & 0x80000000u) ? ~u : (u | 0x80000000u);
}
__device__ __forceinline__ float dec_f32(u32 e) {
    u32 u = (e & 0x80000000u) ? (e & 0x7FFFFFFFu) : ~e;
    return __uint_as_float(u);
}
__device__ __forceinline__ float bcast(float v, int ii) {
    return __uint_as_float(__builtin_amdgcn_readlane(__float_as_uint(v), ii));
}
__device__ __forceinline__ u64 rl64(u64 v, int l) {
    u32 lo = __builtin_amdgcn_readlane((u32)(v & 0xFFFFFFFFull), l);
    u32 hi = __builtin_amdgcn_readlane((u32)(v >> 32), l);
    return ((u64)hi << 32) | (u64)lo;
}
// packed-layout helpers: width (padded even) and word offset of block B
__device__ __forceinline__ int wpad(int B) { return 32 - B + (B & 1); }
__device__ __forceinline__ int soff(int B) { return 32 * B - (B * (B - 1)) / 2 + (B >> 1); }
// async global->LDS, 16B per lane; lds dest = uniform base + lane*16
__device__ __forceinline__ void gload_lds16(const void* g, void* lds) {
    __builtin_amdgcn_global_load_lds(
        (const __attribute__((address_space(1))) void*)g,
        (__attribute__((address_space(3))) void*)lds, 16, 0, 0);
}
// LDS-ordered barrier WITHOUT vmcnt drain (keeps global loads in flight)
__device__ __forceinline__ void bar_lds() {
    asm volatile("s_waitcnt lgkmcnt(0)" ::: "memory");
    __builtin_amdgcn_s_barrier();
    __builtin_amdgcn_sched_barrier(0);
}

// ===========================================================================
// Register-resident bitonic sort: 256 threads x 8 elements, e = tid*8 + r.
// ===========================================================================
template<int J>
__device__ __forceinline__ void reg_pass(u64 v[8], int tid, int k) {
    #pragma unroll
    for (int r = 0; r < 8; ++r) {
        if (!(r & J)) {
            bool desc = (((tid * 8 + r) & k) == 0);
            u64 a = v[r], b = v[r | J];
            u64 mx = a > b ? a : b, mn = a > b ? b : a;
            v[r]     = desc ? mx : mn;
            v[r | J] = desc ? mn : mx;
        }
    }
}

__device__ __forceinline__ void shfl_pass(u64 v[8], int tid, int k, int d) {
    const bool upper = (tid & d) == 0;
    const bool desc = (((tid * 8) & k) == 0);
    const bool keepmax = (desc == upper);
    #pragma unroll
    for (int r = 0; r < 8; ++r) {
        u64 pv = __shfl_xor(v[r], d);
        u64 mx = v[r] > pv ? v[r] : pv, mn = v[r] > pv ? pv : v[r];
        v[r] = keepmax ? mx : mn;
    }
}

__device__ __forceinline__ void lds_pass(u64 v[8], int tid, u64* sm, int k, int d) {
    __syncthreads();
    #pragma unroll
    for (int r = 0; r < 8; ++r) sm[r * 256 + tid] = v[r];
    __syncthreads();
    const bool upper = (tid & d) == 0;
    const bool desc = (((tid * 8) & k) == 0);
    const bool keepmax = (desc == upper);
    const int pt = tid ^ d;
    #pragma unroll
    for (int r = 0; r < 8; ++r) {
        u64 pv = sm[r * 256 + pt];
        u64 mx = v[r] > pv ? v[r] : pv, mn = v[r] > pv ? pv : v[r];
        v[r] = keepmax ? mx : mn;
    }
}

__device__ __forceinline__ void sort2048_desc(u64 v[8], int tid, u64* sm) {
    reg_pass<1>(v, tid, 2);
    reg_pass<2>(v, tid, 4); reg_pass<1>(v, tid, 4);
    for (int k = 8; k <= 2048; k <<= 1) {
        for (int j = k >> 1; j >= 8; j >>= 1) {
            int d = j >> 3;
            if (d <= 32) shfl_pass(v, tid, k, d);
            else         lds_pass(v, tid, sm, k, d);
        }
        reg_pass<4>(v, tid, k); reg_pass<2>(v, tid, k); reg_pass<1>(v, tid, k);
    }
}

// Bitonic cleanup (all-descending), j = 1024..1 — for the top-2048 merge.
__device__ __forceinline__ void cleanup2048_desc(u64 v[8], int tid, u64* sm) {
    lds_pass(v, tid, sm, 4096, 128);   // j = 1024
    lds_pass(v, tid, sm, 4096, 64);    // j = 512
    for (int d = 32; d >= 1; d >>= 1) shfl_pass(v, tid, 4096, d);
    reg_pass<4>(v, tid, 4096); reg_pass<2>(v, tid, 4096); reg_pass<1>(v, tid, 4096);
}

// ---------------------------------------------------------------------------
// Kernel 1: scores -> sortable u64 keys.  grid (96, BATCH), block 256.
// ---------------------------------------------------------------------------
__global__ void score_kernel(const float* __restrict__ yp, u64* __restrict__ keys) {
    __shared__ float tile[128 * ROWF];   // 43520 B
    const int tileIdx = blockIdx.x;
    const int b = blockIdx.y;
    const int tid = threadIdx.x;
    const int batch_lim = NROW * ROWF;       // 904995
    const int tile_base = tileIdx * 128 * ROWF;

    if (tile_base < batch_lim) {
        const float* src = yp + (long long)b * batch_lim + tile_base;
        int lim_e = batch_lim - tile_base;
        if (lim_e > 128 * ROWF) lim_e = 128 * ROWF;
        const int head = (4 - ((3 * b) & 3)) & 3;
        if (lim_e >= 8) {
            const int nv = (lim_e - head) >> 2;
            for (int e = tid; e < head; e += 256) tile[e] = src[e];
            const float4* s4 = (const float4*)(src + head);
            for (int q = tid; q < nv; q += 256) {
                float4 v = s4[q];
                int o = head + q * 4;
                tile[o] = v.x; tile[o + 1] = v.y; tile[o + 2] = v.z; tile[o + 3] = v.w;
            }
            for (int e = head + nv * 4 + tid; e < lim_e; e += 256) tile[e] = src[e];
        } else {
            for (int e = tid; e < lim_e; e += 256) tile[e] = src[e];
        }
    }
    __syncthreads();

    {
        const int row = tid >> 1;                // 0..127
        const int half = tid & 1;                // 0: cls 0..39, 1: cls 40..79
        int gr = tileIdx * 128 + row;
        const float* r = &tile[row * ROWF];
        float m = r[5 + half * 40];
        #pragma unroll
        for (int c = 1; c < 40; ++c) m = fmaxf(m, r[5 + half * 40 + c]);
        float mo = __uint_as_float(__shfl_xor(__float_as_uint(m), 1));
        if (half == 0 && gr < NROW) {
            float s = r[4] * fmaxf(m, mo);
            keys[(long long)b * MPAD + gr] =
                ((u64)enc_f32(s) << 32) | (u64)(0xFFFFFFFFu - (u32)gr);
        } else if (half == 0) {
            keys[(long long)b * MPAD + gr] = 0ULL;   // gr in [NROW, 12288)
        }
    }
}

// ---------------------------------------------------------------------------
// Kernel 2a: sort each 2048-chunk descending.  grid (6, BATCH), block 256.
// ---------------------------------------------------------------------------
__global__ void chunk_sort_kernel(u64* __restrict__ keys) {
    __shared__ u64 sm[2048];
    const int b = blockIdx.y, c = blockIdx.x, tid = threadIdx.x;
    u64* base = keys + (long long)b * MPAD + c * 2048;
    u64 v[8];
    #pragma unroll
    for (int r = 0; r < 8; ++r) v[r] = base[tid * 8 + r];
    sort2048_desc(v, tid, sm);
    #pragma unroll
    for (int r = 0; r < 8; ++r) base[tid * 8 + r] = v[r];
}

// ---------------------------------------------------------------------------
// Kernel 2b: round 1 — (0,1)->B0, (2,3)->B1, (4,5)->B2.  grid (3, BATCH).
// ---------------------------------------------------------------------------
__global__ void merge_r1_kernel(const u64* __restrict__ keysA, u64* __restrict__ keysB) {
    __shared__ u64 sm[2048];
    const int b = blockIdx.y, c = blockIdx.x, tid = threadIdx.x;
    const u64* a = keysA + (long long)b * MPAD + c * 4096;
    u64 v[8];
    #pragma unroll
    for (int r = 0; r < 8; ++r) {
        int e = tid * 8 + r;
        u64 va = a[e], vb = a[4095 - e];
        v[r] = va > vb ? va : vb;
    }
    cleanup2048_desc(v, tid, sm);
    u64* d = keysB + (long long)b * MPAD + c * 2048;
    #pragma unroll
    for (int r = 0; r < 8; ++r) d[tid * 8 + r] = v[r];
}

// ---------------------------------------------------------------------------
// Kernel 2c (fused r2+r3): (B0,B1)->X, (X,B2)->final top-2048 + gather.
// grid: BATCH, block 256.  Bit-identical tree to the 3-kernel chain.
// ---------------------------------------------------------------------------
__global__ void merge_r23_gather_kernel(const u64* __restrict__ keysB,
                                        const float* __restrict__ yp,
                                        float* __restrict__ sx1, float* __restrict__ sy1,
                                        float* __restrict__ sx2, float* __restrict__ sy2,
                                        float* __restrict__ sar, float* __restrict__ ssc) {
    __shared__ u64 sm[2048];
    const int b = blockIdx.x, tid = threadIdx.x;
    const u64* a = keysB + (long long)b * MPAD;
    u64 v[8];
    #pragma unroll
    for (int r = 0; r < 8; ++r) {
        int e = tid * 8 + r;
        u64 va = a[e], vb = a[2048 + 2047 - e];
        v[r] = va > vb ? va : vb;
    }
    cleanup2048_desc(v, tid, sm);
    #pragma unroll
    for (int r = 0; r < 8; ++r) {
        int e = tid * 8 + r;
        u64 vb = a[4096 + 2047 - e];
        v[r] = v[r] > vb ? v[r] : vb;
    }
    cleanup2048_desc(v, tid, sm);

    #pragma unroll
    for (int r = 0; r < 8; ++r) {
        u64 key = v[r];
        float s = dec_f32((u32)(key >> 32));
        u32 idx = 0xFFFFFFFFu - (u32)(key & 0xFFFFFFFFu);
        const float* rp = yp + (long long)b * NROW * ROWF + (long long)idx * ROWF;
        float x = rp[0], y = rp[1], w = rp[2], h = rp[3];
        float hx = w * 0.5f, hy = h * 0.5f;
        float a1 = x - hx, b1 = y - hy, a2 = x + hx, b2 = y + hy;
        int o = b * KTOP + tid * 8 + r;
        sx1[o] = a1; sy1[o] = b1; sx2[o] = a2; sy2[o] = b2;
        sar[o] = fmaxf(a2 - a1, 0.f) * fmaxf(b2 - b1, 0.f);
        ssc[o] = s;
    }
}

// ---------------------------------------------------------------------------
// Kernel 3: pairwise suppression bitmask -> PACKED upper-tri layout + dense
// diagonal side-array.  Block B occupies packed[64*S(B) .. ) with row width
// wpad(B) (columns B..31, pad to even).  grid (132, BATCH), block 256.
// ---------------------------------------------------------------------------
__global__ void mask_kernel(const float* __restrict__ sx1, const float* __restrict__ sy1,
                            const float* __restrict__ sx2, const float* __restrict__ sy2,
                            const float* __restrict__ sar, u64* __restrict__ packed,
                            u64* __restrict__ diag) {
    const int b = blockIdx.y;
    const int t = blockIdx.x * 4 + (threadIdx.x >> 6);   // 0..527
    const int lane = threadIdx.x & 63;

    int rb = (int)((65.0f - sqrtf(4225.0f - 8.0f * (float)t)) * 0.5f);
    while (rb * (65 - rb) / 2 > t) --rb;
    while ((rb + 1) * (64 - rb) / 2 <= t) ++rb;
    const int cb = rb + t - rb * (65 - rb) / 2;

    const int oi = b * KTOP + rb * 64 + lane;
    const int oj = b * KTOP + cb * 64 + lane;
    const float rx1 = sx1[oi], ry1 = sy1[oi], rx2 = sx2[oi], ry2 = sy2[oi], ra = sar[oi];
    const float cx1 = sx1[oj], cy1 = sy1[oj], cx2 = sx2[oj], cy2 = sy2[oj], ca = sar[oj];
    const bool dg = (rb == cb);

    u64 myword = 0ULL;
    for (int ii = 0; ii < 64; ++ii) {
        float ax1 = bcast(rx1, ii), ay1 = bcast(ry1, ii);
        float ax2 = bcast(rx2, ii), ay2 = bcast(ry2, ii);
        float aa  = bcast(ra,  ii);
        float ix1 = fmaxf(ax1, cx1);
        float iy1 = fmaxf(ay1, cy1);
        float ix2 = fminf(ax2, cx2);
        float iy2 = fminf(ay2, cy2);
        float inter = fmaxf(ix2 - ix1, 0.f) * fmaxf(iy2 - iy1, 0.f);
        float uni = aa + ca - inter;
        float iou = inter / fmaxf(uni, 1e-9f);
        bool cond = (iou > IOU_THR) && (!dg || (lane > ii));
        u64 bal = __ballot(cond);
        if (lane == ii) myword = bal;
    }
    const int wB = wpad(rb);
    packed[(long long)b * PKWORDS + 64 * soff(rb) + lane * wB + (cb - rb)] = myword;
    if (dg) diag[(long long)b * 2048 + rb * 64 + lane] = myword;
}

// ---------------------------------------------------------------------------
// Kernel 4: greedy reduce, cooperative split, PACKED mask blocks.
//   Per-iter DMA bytes drop 16KB -> 512*wpad(w) B (avg ~8.7KB) with fully
//   linear gload_lds16 (packed region is contiguous).  Skeleton identical to
//   the proven r13/r16 variant: wave0 readlane chain + dia register prefetch;
//   waves1-3 4-slot ring with counted vmcnt; phase2 cooperative OR.
// grid: BATCH, block: 256.
// ---------------------------------------------------------------------------
__global__ void nms_out_kernel(const float* __restrict__ sx1, const float* __restrict__ sy1,
                               const float* __restrict__ sx2, const float* __restrict__ sy2,
                               const float* __restrict__ ssc,
                               const u64* __restrict__ packed,
                               const u64* __restrict__ diag, float* __restrict__ out) {
    __shared__ u64 slots[4][2048];  // 64 KiB ring; block B uses 64*wpad(B) words <= 2048
    __shared__ u64 pend[8][32];     // supp partials
    __shared__ u64 curs;            // published cur of current block
    __shared__ u64 sbits64[32];     // score-valid bits
    __shared__ u64 keepw[32];
    const int b = blockIdx.x;
    const int tid = threadIdx.x;
    const int lane = tid & 63;
    const int wave = tid >> 6;
    const u64* pk = packed + (long long)b * PKWORDS;
    const u64* dg = diag + (long long)b * 2048;

    auto issue_block = [&](int B) {
        const char* src = (const char*)(pk + (size_t)64 * soff(B));
        char* dst = (char*)&slots[B & 3][0];
        const int nch = wpad(B) >> 1;            // 1KB chunks
        for (int i = 0; i < nch; ++i)
            gload_lds16(src + i * 1024 + lane * 16, dst + i * 1024);
    };

    // ---- prologue ----
    {
        const float* sp = ssc + b * KTOP + tid * 8;
        float4 sa = *(const float4*)(sp);
        float4 sb = *(const float4*)(sp + 4);
        unsigned bits =
            (unsigned)(sa.x > SCORE_THR)       | ((unsigned)(sa.y > SCORE_THR) << 1) |
            ((unsigned)(sa.z > SCORE_THR) << 2) | ((unsigned)(sa.w > SCORE_THR) << 3) |
            ((unsigned)(sb.x > SCORE_THR) << 4) | ((unsigned)(sb.y > SCORE_THR) << 5) |
            ((unsigned)(sb.z > SCORE_THR) << 6) | ((unsigned)(sb.w > SCORE_THR) << 7);
        ((unsigned char*)sbits64)[tid] = (unsigned char)bits;
    }
    u64 dia = 0ULL;
    if (wave == 0) dia = dg[lane];          // block 0 diagonal words
    if (wave >= 1) issue_block(wave - 1);   // blocks 0,1,2
    __syncthreads();   // full drain: blocks 0-2 resident, sbits + dia ready

    u64 myw = 0ULL;
    if (wave == 0 && lane < 32) myw = sbits64[lane];

    // ---- main loop ----
    #pragma unroll 1
    for (int w = 0; w < 32; ++w) {
        const u64* blk = &slots[w & 3][0];

        if (wave == 0) {
            // issue next block's dia load FIRST (latency hides under chain+barriers)
            u64 dia_next = 0ULL;
            if (w < 31) dia_next = dg[(w + 1) * 64 + lane];
            // current keep word -> uniform via dynamic-index readlane
            u64 cur = rl64(myw, w);
            // serial chain: 4 batches of (16 indep readlane-pairs + 16 SALU steps)
            #pragma unroll
            for (int p = 0; p < 4; ++p) {
                u64 dd[16];
                #pragma unroll
                for (int i = 0; i < 16; ++i) dd[i] = rl64(dia, p * 16 + i);
                #pragma unroll
                for (int i = 0; i < 16; ++i) {
                    u64 m = ((cur >> (p * 16 + i)) & 1ULL) ? dd[i] : 0ULL;
                    cur &= ~m;
                }
            }
            if (lane == 0) curs = cur;
            dia = dia_next;
        } else {
            const int rr = wave - 1;
            if ((w % 3) == rr && w + 3 < 32) issue_block(w + 3);
            if (((w + 1) % 3) == rr)
                asm volatile("s_waitcnt vmcnt(0)" ::: "memory");  // my block w+1 landed
        }
        bar_lds();   // barrier 1: cur visible; block w resident for everyone

        // phase 2: cooperative supp partials over packed block w
        {
            u64 curv = curs;                     // LDS broadcast
            const int col = tid & 31;
            const int rg  = tid >> 5;            // row group 0..7 (rows rg*8..+8)
            const int wB = wpad(w);
            int jo = col - w; if (jo < 0) jo = 0;   // cols < w: garbage, never applied
            const u64* rp = blk + (size_t)(rg * 8) * wB + jo;
            u32 bits8 = (u32)(curv >> (rg * 8)) & 0xFFu;
            u64 acc = 0ULL;
            #pragma unroll
            for (int i = 0; i < 8; ++i) {
                u64 t = rp[(size_t)i * wB];
                acc |= ((bits8 >> i) & 1u) ? t : 0ULL;
            }
            pend[rg][col] = acc;
        }
        bar_lds();   // barrier 2: pend complete

        if (wave == 0 && lane < 32) {
            u64 cur = curs;
            u64 s = ((pend[0][lane] | pend[1][lane]) | (pend[2][lane] | pend[3][lane]))
                  | ((pend[4][lane] | pend[5][lane]) | (pend[6][lane] | pend[7][lane]));
            if (lane == w) myw = cur;
            else if (lane > w) myw &= ~s;
        }
        // wave0's pend reads complete before it reaches barrier1 of iter w+1,
        // which is when pend can next be overwritten -> no extra barrier.
    }

    if (wave == 0 && lane < 32) keepw[lane] = myw;
    __syncthreads();

    for (int t = tid; t < KTOP; t += 256) {
        int o = b * KTOP + t;
        float f = ((keepw[t >> 6] >> (t & 63)) & 1ULL) ? 1.0f : 0.0f;
        float* op = out + (long long)o * 5;
        op[0] = sx1[o] * f;
        op[1] = sy1[o] * f;
        op[2] = sx2[o] * f;
        op[3] = sy2[o] * f;
        op[4] = ssc[o] * f;
    }
}

// ---------------------------------------------------------------------------
extern "C" void kernel_launch(void* const* d_in, const int* in_sizes, int n_in,
                              void* d_out, int out_size, void* d_ws, size_t ws_size,
                              hipStream_t stream) {
    const float* yp = (const float*)d_in[0];
    float* out = (float*)d_out;
    char* ws = (char*)d_ws;

    // Workspace layout (aliasing safe by kernel ordering):
    //   [0, 2MiB)   keysA   (dead after merge_r1)
    //   [2, 4MiB)   keysB   (dead after merge_r23)
    //   [0, ~4.5MiB) packed mask (written by mask_kernel, after keys die)
    //   [8MiB, +768KiB)  SoA arrays
    //   [+256KiB)   diag array
    const size_t KEYS_BYTES = (size_t)BATCH * MPAD * sizeof(u64);        // 2 MiB
    const size_t MASK_BYTES = (size_t)BATCH * KTOP * 32 * sizeof(u64);   // 8 MiB (offset anchor)
    const size_t SOA_BYTES  = (size_t)6 * BATCH * KTOP * sizeof(float);  // 768 KiB
    u64* keysA  = (u64*)ws;
    u64* keysB  = (u64*)(ws + KEYS_BYTES);
    u64* packed = (u64*)ws;                       // BATCH*PKWORDS*8 ≈ 4.46 MiB
    float* soa  = (float*)(ws + MASK_BYTES);
    u64* diag   = (u64*)(ws + MASK_BYTES + SOA_BYTES);
    const int SA = BATCH * KTOP;
    float* sx1 = soa + 0 * SA;
    float* sy1 = soa + 1 * SA;
    float* sx2 = soa + 2 * SA;
    float* sy2 = soa + 3 * SA;
    float* sar = soa + 4 * SA;
    float* ssc = soa + 5 * SA;

    score_kernel<<<dim3(96, BATCH), 256, 0, stream>>>(yp, keysA);
    chunk_sort_kernel<<<dim3(6, BATCH), 256, 0, stream>>>(keysA);
    merge_r1_kernel<<<dim3(3, BATCH), 256, 0, stream>>>(keysA, keysB);
    merge_r23_gather_kernel<<<BATCH, 256, 0, stream>>>(keysB, yp,
                                                       sx1, sy1, sx2, sy2, sar, ssc);
    mask_kernel<<<dim3(132, BATCH), 256, 0, stream>>>(sx1, sy1, sx2, sy2, sar,
                                                      packed, diag);
    nms_out_kernel<<<BATCH, 256, 0, stream>>>(sx1, sy1, sx2, sy2, ssc,
                                              packed, diag, out);
}